// Round 8
// baseline (396.836 us; speedup 1.0000x reference)
//
#include <hip/hip_runtime.h>
#include <hip/hip_bf16.h>
#include <stdint.h>

// 2-layer LSTM (H=64) fused over T=336, B=4096, + final linear->sigmoid.
// PRODUCER-CONSUMER WAVE SPECIALIZATION: no block barrier in the main loop.
//  - L0 group (waves 0,2,4,6): runs the layer-0 recurrence, publishes h0(t)
//    into an 8-deep LDS ring; syncs only among its own 4 waves via LDS flags.
//  - L1 group (waves 1,3,5,7): chases 1..7 steps behind, reads h0(tau) from
//    the ring, runs layer-1 recurrence (own 4-wave flag sync), back-pressure
//    keeps the ring safe.
// The groups drift freely -> each group's critical path is its own recurrence,
// and the co-resident other-role wave on each SIMD fills stall windows.
// Nonlin: exchange-free quad-reciprocal (exact): 6.5 trans/element.

typedef __attribute__((ext_vector_type(8))) short s16x8;
typedef __attribute__((ext_vector_type(4))) float f32x4;

#define MFMA_BF16 __builtin_amdgcn_mfma_f32_16x16x32_bf16
#define LOG2E     1.4426950408889634f
#define TWO_LOG2E 2.8853900817779268f
#define DEPTH     8          // h0 ring depth (power of 2)

static __device__ __forceinline__ short f2bf(float f) {
    uint32_t u = __builtin_bit_cast(uint32_t, f);
    u += 0x7fffu + ((u >> 16) & 1u);   // round-to-nearest-even
    return (short)(u >> 16);
}
static __device__ __forceinline__ float fexp2(float t){ return __builtin_amdgcn_exp2f(t); }
static __device__ __forceinline__ float frcp (float t){ return __builtin_amdgcn_rcpf(t); }
static __device__ __forceinline__ float fclampf(float v, float lo, float hi){
    return fminf(fmaxf(v, lo), hi);
}

// wait until all 4 counters >= need (counters hold completed_step + 1)
static __device__ __forceinline__ void spin4(const uint32_t* c, uint32_t need) {
    const volatile uint32_t* vc = (const volatile uint32_t*)c;
    for (;;) {
        uint32_t m0 = vc[0], m1 = vc[1], m2 = vc[2], m3 = vc[3];
        uint32_t mn = min(min(m0, m1), min(m2, m3));
        if (mn >= need) break;
        __builtin_amdgcn_s_sleep(1);
    }
    __builtin_amdgcn_sched_barrier(0);   // keep data reads after the spin
}

// 4-element LSTM nonlinearity, quad-rcp (exact algebra): acc[m][r] -> h[r]
static __device__ __forceinline__ f32x4 nonlin4(const f32x4 acc[4], f32x4& c, uint2& pk) {
    float ov[4], eg[4];
    f32x4 h;
    #pragma unroll
    for (int r = 0; r < 4; ++r) {
        float t0 = fclampf(acc[0][r], -30.f, 30.f);   // i  (pre * -log2e)
        float t1 = fclampf(acc[1][r], -30.f, 30.f);   // f
        float t2 = fclampf(acc[2][r], -30.f, 30.f);   // g  (pre * 2log2e)
        float t3 = fclampf(acc[3][r], -30.f, 30.f);   // o
        float d0 = 1.f + fexp2(t0), d1 = 1.f + fexp2(t1);
        float d2 = 1.f + fexp2(t2), d3 = 1.f + fexp2(t3);
        float p01 = d0 * d1, p23 = d2 * d3;
        float rr  = frcp(p01 * p23);
        float q01 = rr * p23, q23 = rr * p01;         // 1/(d0 d1), 1/(d2 d3)
        float iv = q01 * d1, fv = q01 * d0;           // 1/d0, 1/d1
        float gv = fmaf(-2.f, q23 * d3, 1.f);         // tanh
        ov[r] = q23 * d2;                             // 1/d3
        c[r] = fmaf(fv, c[r], iv * gv);
        eg[r] = fexp2(fclampf(c[r] * TWO_LOG2E, -28.f, 28.f));
    }
    {   float dg0 = 1.f + eg[0], dg1 = 1.f + eg[1];
        float rg = frcp(dg0 * dg1);
        h[0] = ov[0] * fmaf(-2.f, rg * dg1, 1.f);
        h[1] = ov[1] * fmaf(-2.f, rg * dg0, 1.f); }
    {   float dg2 = 1.f + eg[2], dg3 = 1.f + eg[3];
        float rg = frcp(dg2 * dg3);
        h[2] = ov[2] * fmaf(-2.f, rg * dg3, 1.f);
        h[3] = ov[3] * fmaf(-2.f, rg * dg2, 1.f); }
    uint32_t a_, b_;
    asm("v_cvt_pk_bf16_f32 %0, %1, %2" : "=v"(a_) : "v"(h[0]), "v"(h[1]));
    asm("v_cvt_pk_bf16_f32 %0, %1, %2" : "=v"(b_) : "v"(h[2]), "v"(h[3]));
    pk = make_uint2(a_, b_);
    return h;
}

__global__ __launch_bounds__(512, 1)
void lstm_fused(const float* __restrict__ x,
                const float* __restrict__ w_ih0, const float* __restrict__ w_hh0,
                const float* __restrict__ b_ih0, const float* __restrict__ b_hh0,
                const float* __restrict__ w_ih1, const float* __restrict__ w_hh1,
                const float* __restrict__ b_ih1, const float* __restrict__ b_hh1,
                const float* __restrict__ w_lin, const float* __restrict__ b_lin,
                float* __restrict__ out)
{
    __shared__ __align__(16) short    xs[16 * 512];        // 16 KB x-chunk bf16 (K-pad 32)
    __shared__ __align__(16) uint32_t h0r[DEPTH][512];     // 16 KB h0 ring (bf16-pairs)
    __shared__ __align__(16) uint32_t h1s[2][512];         //  4 KB h1 double buffer
    __shared__ __align__(16) uint32_t cnt[32];             // 0-3:l0  8-11:l1  16-19:stage
    __shared__ float red[4][16];

    const int tid  = threadIdx.x;
    const int w    = tid >> 6;       // wave 0..7
    const int role = w & 1;          // 0 = layer0 (producer), 1 = layer1 (consumer)
    const int wl   = w >> 1;         // wave-within-role: j-slice [16wl,16wl+16)
    const int l    = tid & 63;
    const int bcol = l & 15;
    const int q    = l >> 4;
    const int b0   = blockIdx.x * 16;

    for (int i = tid; i < 16 * 512; i += 512) xs[i] = 0;
    if (tid < 512) {
        #pragma unroll
        for (int s = 0; s < DEPTH; ++s) h0r[s][tid] = 0;
        h1s[0][tid] = 0; h1s[1][tid] = 0;
    }
    if (tid < 32) cnt[tid] = 0;
    __syncthreads();

    // sigma(x)=1/(1+2^(-x log2e)); tanh(x)=1-2/(1+2^(2x log2e)) — scales folded.
    const float scm[4] = { -LOG2E, -LOG2E, TWO_LOG2E, -LOG2E };

    // Weight A-frags, unioned across roles (lane holds A[row=bcol][k=q*8+r]):
    // role0: aW[m]=W_ih0 (K 9->32 pad), aW[4+m]=W_hh0[:,0:32), aW[8+m]=W_hh0[:,32:64)
    // role1: aW[m]=W_ih1[:,0:32), aW[4+m]=W_ih1[:,32:64),
    //        aW[8+m]=W_hh1[:,0:32), aW[12+m]=W_hh1[:,32:64)
    s16x8 aW[16];
    f32x4 bias[4];
    #pragma unroll
    for (int m = 0; m < 4; ++m) {
        const int R = m * 64 + wl * 16 + bcol;
        const float sc = scm[m];
        if (role == 0) {
            #pragma unroll
            for (int r = 0; r < 8; ++r) {
                int k = q * 8 + r;
                aW[m][r] = (k < 9) ? f2bf(w_ih0[R * 9 + k] * sc) : (short)0;
            }
            const float* pA = w_hh0 + R * 64 + q * 8;
            const float* pB = w_hh0 + R * 64 + 32 + q * 8;
            #pragma unroll
            for (int r = 0; r < 8; ++r) {
                aW[4 + m][r]  = f2bf(pA[r] * sc);
                aW[8 + m][r]  = f2bf(pB[r] * sc);
                aW[12 + m][r] = 0;
            }
        } else {
            const float* pA = w_ih1 + R * 64 + q * 8;
            const float* pB = w_ih1 + R * 64 + 32 + q * 8;
            const float* pC = w_hh1 + R * 64 + q * 8;
            const float* pD = w_hh1 + R * 64 + 32 + q * 8;
            #pragma unroll
            for (int r = 0; r < 8; ++r) {
                aW[m][r]      = f2bf(pA[r] * sc);
                aW[4 + m][r]  = f2bf(pB[r] * sc);
                aW[8 + m][r]  = f2bf(pC[r] * sc);
                aW[12 + m][r] = f2bf(pD[r] * sc);
            }
        }
        const float* bi = (role == 0) ? b_ih0 : b_ih1;
        const float* bh = (role == 0) ? b_hh0 : b_hh1;
        #pragma unroll
        for (int r = 0; r < 4; ++r) {
            int G = m * 64 + wl * 16 + q * 4 + r;
            bias[m][r] = (bi[G] + bh[G]) * sc;
        }
    }

    // h buffers: u32 H[b][p], p=j>>1, stored at p ^ ((b&7)<<2).
    const int hswz = (bcol & 7) << 2;
    const int hk0  = bcol * 32 + ((q * 4) ^ hswz);          // frag kf0: 4 consec u32
    const int hk1  = bcol * 32 + ((16 + q * 4) ^ hswz);     // frag kf1
    const int hwp  = bcol * 32 + ((wl * 8 + q * 2) ^ hswz); // write: 2 consec u32
    const int xrd  = bcol * 32 + ((q ^ (bcol & 3)) << 3);   // shorts

    // staging map (role-0 group = 256 lanes)
    const int    sidx  = wl * 64 + l;
    const int    ld_b  = sidx >> 4, ld_t = sidx & 15;
    const float* xrow  = x + (size_t)(b0 + ld_b) * (336 * 9) + ld_t * 9;
    const int    xs_wr = ld_t * 512 + ld_b * 32;
    const int    xswzw = (ld_b & 3) << 3;

    uint32_t* const l0c = &cnt[0];
    uint32_t* const l1c = &cnt[8];
    uint32_t* const stc = &cnt[16];

    f32x4 c  = {0.f, 0.f, 0.f, 0.f};
    f32x4 hq = {0.f, 0.f, 0.f, 0.f};    // role1 keeps h1(335)
    f32x4 acc[4];

    if (role == 0) {
        // =================== producer: layer-0 recurrence ===================
        #pragma unroll 1
        for (int t = 0; t < 336; ++t) {
            spin4(l0c, t);                                   // own group done t-1
            if ((t & 15) == 0) {                             // stage x chunk
                const int ck = t >> 4;
                const float* xp = xrow + (size_t)t * 9;
                #pragma unroll
                for (int d = 0; d < 9; ++d)
                    xs[(xs_wr + d) ^ xswzw] = f2bf(xp[d]);
                __threadfence_block();
                if (l == 0) *(volatile uint32_t*)&stc[wl] = ck + 1;
                spin4(stc, ck + 1);
            }
            s16x8 bx = *(const s16x8*)&xs[(t & 15) * 512 + xrd];
            const uint32_t* hp = h0r[(t + DEPTH - 1) & (DEPTH - 1)];   // h0(t-1)
            s16x8 ba = *(const s16x8*)&hp[hk0];
            s16x8 bb = *(const s16x8*)&hp[hk1];
            if (t >= DEPTH - 2) spin4(l1c, (uint32_t)(t - (DEPTH - 2)));  // ring WAR
            #pragma unroll
            for (int m = 0; m < 4; ++m) acc[m] = MFMA_BF16(aW[m],     bx, bias[m], 0, 0, 0);
            #pragma unroll
            for (int m = 0; m < 4; ++m) acc[m] = MFMA_BF16(aW[4 + m], ba, acc[m],  0, 0, 0);
            #pragma unroll
            for (int m = 0; m < 4; ++m) acc[m] = MFMA_BF16(aW[8 + m], bb, acc[m],  0, 0, 0);
            uint2 pk;
            nonlin4(acc, c, pk);
            *(uint2*)&h0r[t & (DEPTH - 1)][hwp] = pk;
            __threadfence_block();
            if (l == 0) *(volatile uint32_t*)&l0c[wl] = t + 1;
        }
    } else {
        // =================== consumer: layer-1 recurrence ===================
        #pragma unroll 1
        for (int t = 0; t < 336; ++t) {
            spin4(l0c, t + 1);                               // h0(t) published
            const uint32_t* hp = h0r[t & (DEPTH - 1)];
            s16x8 ba = *(const s16x8*)&hp[hk0];
            s16x8 bb = *(const s16x8*)&hp[hk1];
            spin4(l1c, t);                                   // own group done t-1
            const uint32_t* h1p = h1s[(t + 1) & 1];          // h1(t-1)
            s16x8 b1a = *(const s16x8*)&h1p[hk0];
            s16x8 b1b = *(const s16x8*)&h1p[hk1];
            #pragma unroll
            for (int m = 0; m < 4; ++m) acc[m] = MFMA_BF16(aW[m],      ba,  bias[m], 0, 0, 0);
            #pragma unroll
            for (int m = 0; m < 4; ++m) acc[m] = MFMA_BF16(aW[4 + m],  bb,  acc[m],  0, 0, 0);
            #pragma unroll
            for (int m = 0; m < 4; ++m) acc[m] = MFMA_BF16(aW[8 + m],  b1a, acc[m],  0, 0, 0);
            #pragma unroll
            for (int m = 0; m < 4; ++m) acc[m] = MFMA_BF16(aW[12 + m], b1b, acc[m],  0, 0, 0);
            uint2 pk;
            hq = nonlin4(acc, c, pk);
            *(uint2*)&h1s[t & 1][hwp] = pk;
            __threadfence_block();
            if (l == 0) *(volatile uint32_t*)&l1c[wl] = t + 1;
        }
    }

    __syncthreads();

    // ---- out[b] = sigm(sum_j h1_335[b][j] * w_lin[j] + b_lin) ----
    if (role == 1) {
        const int j0 = wl * 16 + q * 4;
        float part = hq[0] * w_lin[j0 + 0] + hq[1] * w_lin[j0 + 1]
                   + hq[2] * w_lin[j0 + 2] + hq[3] * w_lin[j0 + 3];
        part += __shfl_xor(part, 16, 64);
        part += __shfl_xor(part, 32, 64);
        if (q == 0) red[wl][bcol] = part;
    }
    __syncthreads();
    if (tid < 16) {
        float s = red[0][tid] + red[1][tid] + red[2][tid] + red[3][tid] + b_lin[0];
        out[b0 + tid] = frcp(1.f + fexp2(-s * LOG2E));
    }
}

extern "C" void kernel_launch(void* const* d_in, const int* in_sizes, int n_in,
                              void* d_out, int out_size, void* d_ws, size_t ws_size,
                              hipStream_t stream) {
    const float* x     = (const float*)d_in[0];
    const float* w_ih0 = (const float*)d_in[1];
    const float* w_hh0 = (const float*)d_in[2];
    const float* b_ih0 = (const float*)d_in[3];
    const float* b_hh0 = (const float*)d_in[4];
    const float* w_ih1 = (const float*)d_in[5];
    const float* w_hh1 = (const float*)d_in[6];
    const float* b_ih1 = (const float*)d_in[7];
    const float* b_hh1 = (const float*)d_in[8];
    const float* w_lin = (const float*)d_in[9];
    const float* b_lin = (const float*)d_in[10];

    lstm_fused<<<dim3(256), dim3(512), 0, stream>>>(
        x, w_ih0, w_hh0, b_ih0, b_hh0,
        w_ih1, w_hh1, b_ih1, b_hh1,
        w_lin, b_lin, (float*)d_out);
}

// Round 9
// 334.028 us; speedup vs baseline: 1.1880x; 1.1880x over previous
//
#include <hip/hip_runtime.h>
#include <hip/hip_bf16.h>
#include <stdint.h>

// 2-layer LSTM (H=64) fused over T=336, B=4096, + final linear->sigmoid.
// R4 antiphase structure (best measured) + QUAD-RCP nonlinearity:
//   A:  L0-waves: MFMA(gates0(i));          L1-waves: nonlin->h1(i-2), write
//   B:  L0-waves: nonlin->h0(i), write;     L1-waves: MFMA(gates1(i-1))
// Nonlin cut 10 -> 6.5 trans/element (exact): one rcp over the product of all
// four gate denominators recovers each 1/d via partial products; the two
// cell-tanh rcps are paired the same way.  Clamps are single v_med3_f32.
// gates1 carried in regs across the barrier; h1 single-buffered, h0 double.

typedef __attribute__((ext_vector_type(8))) short s16x8;
typedef __attribute__((ext_vector_type(4))) short s16x4;
typedef __attribute__((ext_vector_type(4))) float f32x4;

#define MFMA_BF16 __builtin_amdgcn_mfma_f32_16x16x32_bf16
#define LOG2E     1.4426950408889634f
#define TWO_LOG2E 2.8853900817779268f

__device__ __forceinline__ short f2bf(float f) {
    uint32_t u = __builtin_bit_cast(uint32_t, f);
    u += 0x7fffu + ((u >> 16) & 1u);   // round-to-nearest-even
    return (short)(u >> 16);
}

__device__ __forceinline__ s16x4 pack_bf16x4(float a, float b, float c, float d) {
    union { uint32_t u[2]; s16x4 s; } r;
    asm("v_cvt_pk_bf16_f32 %0, %1, %2" : "=v"(r.u[0]) : "v"(a), "v"(b));
    asm("v_cvt_pk_bf16_f32 %0, %1, %2" : "=v"(r.u[1]) : "v"(c), "v"(d));
    return r.s;
}

static __device__ __forceinline__ float fexp2(float t){ return __builtin_amdgcn_exp2f(t); }
static __device__ __forceinline__ float frcp (float t){ return __builtin_amdgcn_rcpf(t); }
static __device__ __forceinline__ float fclmp(float v, float lo, float hi){
    return __builtin_amdgcn_fmed3f(v, lo, hi);      // median == clamp, 1 instr
}

// rcp(1 + 2^t) for the final linear stage only
__device__ __forceinline__ float rcp1p2(float t) {
    return frcp(1.0f + fexp2(t));
}

// 4-element LSTM nonlinearity, quad-rcp (exact algebra).
// acc[m][r]: pre-activations already scaled (i,f,o by -log2e; g by +2log2e).
// Updates c[r], returns h[r].  Trans: 20 exp2 + 6 rcp per 4 elems = 6.5/elem.
__device__ __forceinline__ f32x4 nonlin_q(const f32x4 acc[4], f32x4& c) {
    float ov[4], eg[4];
    f32x4 h;
    #pragma unroll
    for (int r = 0; r < 4; ++r) {
        float t0 = fclmp(acc[0][r], -30.f, 30.f);
        float t1 = fclmp(acc[1][r], -30.f, 30.f);
        float t2 = fclmp(acc[2][r], -30.f, 30.f);
        float t3 = fclmp(acc[3][r], -30.f, 30.f);
        float d0 = 1.f + fexp2(t0), d1 = 1.f + fexp2(t1);
        float d2 = 1.f + fexp2(t2), d3 = 1.f + fexp2(t3);
        float p01 = d0 * d1, p23 = d2 * d3;
        float rr  = frcp(p01 * p23);
        float q01 = rr * p23, q23 = rr * p01;       // 1/(d0 d1), 1/(d2 d3)
        float iv = q01 * d1, fv = q01 * d0;         // sigma(i), sigma(f)
        float gv = fmaf(-2.f, q23 * d3, 1.f);       // tanh(g)
        ov[r]    = q23 * d2;                        // sigma(o)
        c[r] = fmaf(fv, c[r], iv * gv);
        eg[r] = fexp2(fclmp(c[r] * TWO_LOG2E, -28.f, 28.f));
    }
    {   float dg0 = 1.f + eg[0], dg1 = 1.f + eg[1];
        float rg = frcp(dg0 * dg1);
        h[0] = ov[0] * fmaf(-2.f, rg * dg1, 1.f);
        h[1] = ov[1] * fmaf(-2.f, rg * dg0, 1.f); }
    {   float dg2 = 1.f + eg[2], dg3 = 1.f + eg[3];
        float rg = frcp(dg2 * dg3);
        h[2] = ov[2] * fmaf(-2.f, rg * dg3, 1.f);
        h[3] = ov[3] * fmaf(-2.f, rg * dg2, 1.f); }
    return h;
}

__global__ __launch_bounds__(512, 1)
void lstm_fused(const float* __restrict__ x,
                const float* __restrict__ w_ih0, const float* __restrict__ w_hh0,
                const float* __restrict__ b_ih0, const float* __restrict__ b_hh0,
                const float* __restrict__ w_ih1, const float* __restrict__ w_hh1,
                const float* __restrict__ b_ih1, const float* __restrict__ b_hh1,
                const float* __restrict__ w_lin, const float* __restrict__ b_lin,
                float* __restrict__ out)
{
    __shared__ __align__(16) short xs[16 * 512];        // 16 KB x-chunk
    __shared__ __align__(16) short h0s[2][16 * 64];     // h0 double buffer
    __shared__ __align__(16) short h1s[16 * 64];        // h1 single buffer
    __shared__ float red[4][16];

    const int tid  = threadIdx.x;
    const int w    = tid >> 6;       // wave 0..7
    const int role = w >> 2;         // 0 = layer0, 1 = layer1
    const int wl   = w & 3;          // j-slice [16wl, 16wl+16)
    const int l    = tid & 63;
    const int bcol = l & 15;
    const int q    = l >> 4;
    const int b0   = blockIdx.x * 16;

    for (int i = tid; i < 16 * 512; i += 512) xs[i] = 0;
    for (int i = tid; i < 16 * 64; i += 512) {
        h0s[0][i] = 0; h0s[1][i] = 0; h1s[i] = 0;
    }
    __syncthreads();

    // sigma(x)=rcp(1+exp2(-x*log2e)); tanh(x)=1-2*rcp(1+exp2(2x*log2e))
    const float scm[4] = { -LOG2E, -LOG2E, TWO_LOG2E, -LOG2E };

    s16x8 aW[4][4];
    f32x4 bias[4];
    #pragma unroll
    for (int m = 0; m < 4; ++m) {
        const int R = m * 64 + wl * 16 + bcol;
        const float sc = scm[m];
        if (role == 0) {
            #pragma unroll
            for (int r = 0; r < 8; ++r) {
                int k = q * 8 + r;
                aW[m][0][r] = (k < 9) ? f2bf(w_ih0[R * 9 + k] * sc) : (short)0;
            }
            #pragma unroll
            for (int kf = 0; kf < 2; ++kf) {
                const float* p = w_hh0 + R * 64 + kf * 32 + q * 8;
                #pragma unroll
                for (int r = 0; r < 8; ++r) aW[m][1 + kf][r] = f2bf(p[r] * sc);
            }
            #pragma unroll
            for (int r = 0; r < 8; ++r) aW[m][3][r] = 0;
            #pragma unroll
            for (int r = 0; r < 4; ++r) {
                int G = m * 64 + wl * 16 + q * 4 + r;
                bias[m][r] = (b_ih0[G] + b_hh0[G]) * sc;
            }
        } else {
            #pragma unroll
            for (int kf = 0; kf < 4; ++kf) {
                int ks = kf * 32 + q * 8;
                const float* p = (ks < 64) ? (w_ih1 + R * 64 + ks)
                                           : (w_hh1 + R * 64 + (ks - 64));
                #pragma unroll
                for (int r = 0; r < 8; ++r) aW[m][kf][r] = f2bf(p[r] * sc);
            }
            #pragma unroll
            for (int r = 0; r < 4; ++r) {
                int G = m * 64 + wl * 16 + q * 4 + r;
                bias[m][r] = (b_ih1[G] + b_hh1[G]) * sc;
            }
        }
    }

    f32x4 c  = {0.f, 0.f, 0.f, 0.f};
    f32x4 hq = {0.f, 0.f, 0.f, 0.f};
    f32x4 accL1[4];                      // L1 pending gates (set in B, used next A)
    #pragma unroll
    for (int m = 0; m < 4; ++m) accL1[m] = (f32x4){0.f, 0.f, 0.f, 0.f};

    const int hrd0 = bcol * 64 + (((q    ) ^ (bcol & 7)) << 3);
    const int hrd1 = bcol * 64 + (((4 + q) ^ (bcol & 7)) << 3);
    const int hwr  = bcol * 64 + (((wl * 2 + (q >> 1)) ^ (bcol & 7)) << 3)
                   + ((q & 1) << 2);
    const int xrd  = bcol * 32 + ((q ^ (bcol & 3)) << 3);

    const int    ld_b = (tid & 255) >> 4, ld_t = tid & 15;
    const float* xrow = x + (size_t)(b0 + ld_b) * (336 * 9) + ld_t * 9;
    const int    xs_wr_base = ld_t * 512 + ld_b * 32;
    const int    xswzw = (ld_b & 3) << 3;

    #pragma unroll 1
    for (int i = 0; i <= 337; ++i) {
        if ((i & 15) == 0 && i < 336) {
            if (tid < 256) {
                const float* xp = xrow + (size_t)i * 9;
                #pragma unroll
                for (int d = 0; d < 9; ++d)
                    xs[(xs_wr_base + d) ^ xswzw] = f2bf(xp[d]);
            }
            __syncthreads();
        }

        // ================= interval A =================
        f32x4 acc0[4];
        if (role == 0) {
            if (i <= 335) {
                s16x8 bx = *(const s16x8*)&xs[(i & 15) * 512 + xrd];
                const short* h0r = h0s[(i & 1) ^ 1];            // h0(i-1)
                s16x8 ba = *(const s16x8*)&h0r[hrd0];
                s16x8 bb = *(const s16x8*)&h0r[hrd1];
                #pragma unroll
                for (int m = 0; m < 4; ++m) acc0[m] = MFMA_BF16(aW[m][0], bx, bias[m], 0, 0, 0);
                #pragma unroll
                for (int m = 0; m < 4; ++m) acc0[m] = MFMA_BF16(aW[m][1], ba, acc0[m], 0, 0, 0);
                #pragma unroll
                for (int m = 0; m < 4; ++m) acc0[m] = MFMA_BF16(aW[m][2], bb, acc0[m], 0, 0, 0);
            }
        } else {
            if (i >= 2) {   // nonlin on gates1(i-2) -> h1(i-2)
                hq = nonlin_q(accL1, c);
                *(s16x4*)&h1s[hwr] = pack_bf16x4(hq[0], hq[1], hq[2], hq[3]);
            }
        }
        __syncthreads();   // B_mid: h1(i-2) visible

        // ================= interval B =================
        if (role == 0) {
            if (i <= 335) {
                f32x4 h0q = nonlin_q(acc0, c);
                short* h0w = h0s[i & 1];                        // h0(i)
                *(s16x4*)&h0w[hwr] = pack_bf16x4(h0q[0], h0q[1], h0q[2], h0q[3]);
            }
        } else {
            if (i >= 1 && i <= 336) {   // gates1(i-1) from h0(i-1), h1(i-2)
                const short* h0r = h0s[(i & 1) ^ 1];            // h0(i-1)
                s16x8 ba  = *(const s16x8*)&h0r[hrd0];
                s16x8 bb  = *(const s16x8*)&h0r[hrd1];
                s16x8 b1a = *(const s16x8*)&h1s[hrd0];
                s16x8 b1b = *(const s16x8*)&h1s[hrd1];
                #pragma unroll
                for (int m = 0; m < 4; ++m) accL1[m] = MFMA_BF16(aW[m][0], ba,  bias[m], 0, 0, 0);
                #pragma unroll
                for (int m = 0; m < 4; ++m) accL1[m] = MFMA_BF16(aW[m][1], bb,  accL1[m], 0, 0, 0);
                #pragma unroll
                for (int m = 0; m < 4; ++m) accL1[m] = MFMA_BF16(aW[m][2], b1a, accL1[m], 0, 0, 0);
                #pragma unroll
                for (int m = 0; m < 4; ++m) accL1[m] = MFMA_BF16(aW[m][3], b1b, accL1[m], 0, 0, 0);
            }
        }
        __syncthreads();   // B_end: h0(i) visible
    }

    // ---- out[b] = sigm(sum_j h1_335[b][j] * w_lin[j] + b_lin) ----
    if (role == 1) {
        float part = hq[0] * w_lin[wl * 16 + q * 4 + 0]
                   + hq[1] * w_lin[wl * 16 + q * 4 + 1]
                   + hq[2] * w_lin[wl * 16 + q * 4 + 2]
                   + hq[3] * w_lin[wl * 16 + q * 4 + 3];
        part += __shfl_xor(part, 16, 64);
        part += __shfl_xor(part, 32, 64);
        if (q == 0) red[wl][bcol] = part;
    }
    __syncthreads();
    if (tid < 16) {
        float s = red[0][tid] + red[1][tid] + red[2][tid] + red[3][tid] + b_lin[0];
        out[b0 + tid] = rcp1p2(-s * LOG2E);
    }
}

extern "C" void kernel_launch(void* const* d_in, const int* in_sizes, int n_in,
                              void* d_out, int out_size, void* d_ws, size_t ws_size,
                              hipStream_t stream) {
    const float* x     = (const float*)d_in[0];
    const float* w_ih0 = (const float*)d_in[1];
    const float* w_hh0 = (const float*)d_in[2];
    const float* b_ih0 = (const float*)d_in[3];
    const float* b_hh0 = (const float*)d_in[4];
    const float* w_ih1 = (const float*)d_in[5];
    const float* w_hh1 = (const float*)d_in[6];
    const float* b_ih1 = (const float*)d_in[7];
    const float* b_hh1 = (const float*)d_in[8];
    const float* w_lin = (const float*)d_in[9];
    const float* b_lin = (const float*)d_in[10];

    lstm_fused<<<dim3(256), dim3(512), 0, stream>>>(
        x, w_ih0, w_hh0, b_ih0, b_hh0,
        w_ih1, w_hh1, b_ih1, b_hh1,
        w_lin, b_lin, (float*)d_out);
}